// Round 1
// baseline (150.976 us; speedup 1.0000x reference)
//
#include <hip/hip_runtime.h>

// Signature-kernel MMD, fused: RBF Gram -> double increments (dyadic p=1 folded
// analytically: inc[i,j] = binc[i/2,j/2]/4) -> Goursat PDE wavefront -> weighted sum.
//
// One wave (64 lanes) per pair; 3*32*32 = 3072 pairs. Lane l owns PDE rows
// i=2l (E) and i=2l+1 (O); cross-lane neighbor (i-1) via __shfl_up -> no
// barriers in the 251-iteration diagonal loop.

constexpr int MD = 126;       // M = (L-1)*2^1 = 126
constexpr int STRIDE = 66;    // LDS row stride: PDE lane stride = 65 mod 32 = 1 -> conflict-free

__global__ void zero_kernel(float* out) {
    out[0] = 0.0f;
}

__global__ __launch_bounds__(64) void sigpde_kernel(const float* __restrict__ x,
                                                    const float* __restrict__ y,
                                                    float* __restrict__ out) {
    __shared__ float Gs[64 * STRIDE];   // Gram, overwritten in place by binc*0.25
    __shared__ float4 xs[64];           // staged A rows for broadcast

    const int lane = threadIdx.x;       // 0..63
    const int p = blockIdx.x;           // 0..3071
    const int g = p >> 10;              // 0: xx, 1: xy, 2: yy
    const int q = p & 1023;
    const int a = q >> 5;
    const int b = q & 31;

    const float* Abase = (g == 2) ? y : x;
    const float* Bbase = (g == 0) ? x : y;

    // Stage A's 64x4 path into LDS; each lane keeps its own B row in registers.
    xs[lane] = ((const float4*)(Abase + a * 256))[lane];
    const float4 yv = ((const float4*)(Bbase + b * 256))[lane];
    __syncthreads();

    // Gram: G[u][lane] = exp(-0.5 * ||x_u - y_lane||^2)   (sigma = 1)
    #pragma unroll 4
    for (int u = 0; u < 64; ++u) {
        float4 xv = xs[u];  // same-address LDS read -> broadcast, no conflict
        float dx = xv.x - yv.x;
        float dy = xv.y - yv.y;
        float dz = xv.z - yv.z;
        float dw = xv.w - yv.w;
        float d2 = dx * dx + dy * dy + dz * dz + dw * dw;
        Gs[u * STRIDE + lane] = __expf(-0.5f * d2);
    }
    __syncthreads();

    // In-place double increments, scaled by 1/4 (dyadic refinement factor):
    // binc[u][v] = (G[u+1][v+1] - G[u+1][v] - G[u][v+1] + G[u][v]) * 0.25
    // Safe in lockstep: each lane's write depends on all 4 of its reads, so all
    // reads of row u (incl. the address lane v-1 reads as v+1) precede the write.
    for (int u = 0; u < 63; ++u) {
        float v00 = Gs[u * STRIDE + lane];
        float v01 = Gs[u * STRIDE + lane + 1];
        float v10 = Gs[(u + 1) * STRIDE + lane];
        float v11 = Gs[(u + 1) * STRIDE + lane + 1];
        float w = 0.25f * (v11 - v10 - v01 + v00);
        if (lane < 63) Gs[u * STRIDE + lane] = w;
    }
    __syncthreads();

    // Goursat PDE over antidiagonals d = 2..2M of the (M+1)x(M+1) K grid.
    // K[i,j] = K[i-1,j] + K[i,j-1] + K[i-1,j-1]*(inc[i-1,j-1]-1), K[0,:]=K[:,0]=1.
    // Diagonal d holds K[i, d-i]. Lane l: E slot i=2l, O slot i=2l+1.
    const int iE = lane * 2;
    const int iO = iE + 1;
    const int rowE = (lane >= 1) ? (lane - 1) : 0;   // (iE-1)/2, clamped
    const int rowO = (lane <= 62) ? lane : 62;       // (iO-1)/2, clamped
    const float* bincE = Gs + rowE * STRIDE;
    const float* bincO = Gs + rowO * STRIDE;

    float p2E = (lane == 0) ? 1.0f : 0.0f;  // diagonal d=0: K[0,0]=1
    float p2O = 0.0f;
    float p1E = (lane == 0) ? 1.0f : 0.0f;  // diagonal d=1: K[0,1]=K[1,0]=1
    float p1O = (lane == 0) ? 1.0f : 0.0f;

    for (int d = 2; d <= 2 * MD; ++d) {
        float up1 = __shfl_up(p1O, 1);   // p1[i-1] for E slot
        float up2 = __shfl_up(p2O, 1);   // p2[i-1] for E slot

        int cE = (d - 1 - iE) >> 1;      // (j-1)/2 for E slot
        cE = min(max(cE, 0), 62);
        int cO = (d - 1 - iO) >> 1;      // (j-1)/2 for O slot
        cO = min(max(cO, 0), 62);
        float incE = bincE[cE];
        float incO = bincO[cO];

        float interE = up1 + p1E + up2 * (incE - 1.0f);
        float interO = p1E + p1O + p2E * (incO - 1.0f);

        bool boundE = (lane == 0) || (d == iE);           // i==0 or j==0 cell
        bool validE = (d >= iE) && (d <= iE + MD);        // iE <= MD always
        float curE = validE ? (boundE ? 1.0f : interE) : 0.0f;

        bool boundO = (d == iO);
        bool validO = (d >= iO) && (d <= iO + MD) && (iO <= MD);
        float curO = validO ? (boundO ? 1.0f : interO) : 0.0f;

        p2E = p1E; p2O = p1O;
        p1E = curE; p1O = curO;
    }

    // K[M,M]: i = 126 = E slot of lane 63, on diagonal d = 2M (now in p1).
    float K = __shfl(p1E, 63);
    if (lane == 0) {
        float wgt = (g == 1) ? (-2.0f / 1024.0f) : (1.0f / 1024.0f);
        atomicAdd(out, wgt * K);
    }
}

extern "C" void kernel_launch(void* const* d_in, const int* in_sizes, int n_in,
                              void* d_out, int out_size, void* d_ws, size_t ws_size,
                              hipStream_t stream) {
    const float* x = (const float*)d_in[0];
    const float* y = (const float*)d_in[1];
    float* out = (float*)d_out;
    (void)in_sizes; (void)n_in; (void)out_size; (void)d_ws; (void)ws_size;

    hipLaunchKernelGGL(zero_kernel, dim3(1), dim3(1), 0, stream, out);
    hipLaunchKernelGGL(sigpde_kernel, dim3(3072), dim3(64), 0, stream, x, y, out);
}

// Round 2
// 105.872 us; speedup vs baseline: 1.4260x; 1.4260x over previous
//
#include <hip/hip_runtime.h>
#include <hip/hip_fp16.h>

// Signature-kernel MMD, fused. One wave per pair (3072 pairs).
// R2: DPP wave-shift instead of ds_bpermute shuffles, boundary handling folded
// into the recurrence seed (zero-propagation), fp16 binc in LDS (9.6 KB/block
// -> 12 resident blocks/CU), software-pipelined LDS reads (1 u16/diagonal).

constexpr int S2 = 66;   // binc row stride in fp16 elements (132 B -> ~2-way banks, free)

__global__ void zero_kernel(float* out) { out[0] = 0.0f; }

__device__ __forceinline__ float dpp_wave_shr1(float v) {
    // result[l] = src[l-1], result[0] = 0  (bound_ctrl)
    return __builtin_bit_cast(float,
        __builtin_amdgcn_update_dpp(0, __builtin_bit_cast(int, v),
                                    0x138, 0xF, 0xF, true));
}
__device__ __forceinline__ float dpp_wave_shl1(float v) {
    // result[l] = src[l+1], result[63] = 0
    return __builtin_bit_cast(float,
        __builtin_amdgcn_update_dpp(0, __builtin_bit_cast(int, v),
                                    0x130, 0xF, 0xF, true));
}

__global__ __launch_bounds__(64) void sigpde_kernel(const float* __restrict__ x,
                                                    const float* __restrict__ y,
                                                    float* __restrict__ out) {
    __shared__ _Float16 binc[63 * S2 + 2];  // binc/4, rows 0..62, cols 0..62 used
    __shared__ float4 xs[64];
    __shared__ float xxs[64];

    const int lane = threadIdx.x;       // 0..63
    const int p = blockIdx.x;           // 0..3071
    const int g = p >> 10;              // 0: xx, 1: xy, 2: yy
    const int q = p & 1023;
    const int a = q >> 5;
    const int b = q & 31;

    const float* Ab = (g == 2) ? y : x;
    const float* Bb = (g == 0) ? x : y;

    float4 xv = ((const float4*)(Ab + a * 256))[lane];
    float4 yv = ((const float4*)(Bb + b * 256))[lane];
    xs[lane] = xv;
    xxs[lane] = xv.x * xv.x + xv.y * xv.y + xv.z * xv.z + xv.w * xv.w;
    const float yy = yv.x * yv.x + yv.y * yv.y + yv.z * yv.z + yv.w * yv.w;
    __syncthreads();

    // Gram rows, streamed: G[u][lane] = exp(-0.5*(xx_u + yy - 2 x_u.y_lane)).
    // Column diff via DPP shl1; row diff streamed via dprev ->
    // binc[u-1][lane] = 0.25*((Gn-G)_u - (Gn-G)_{u-1})   (fp16, cancellation in fp32)
    float dprev = 0.0f;
    #pragma unroll 8
    for (int u = 0; u < 64; ++u) {
        float4 xu = xs[u];
        float dot = xu.x * yv.x + xu.y * yv.y + xu.z * yv.z + xu.w * yv.w;
        float t = xxs[u] + yy - dot - dot;
        float gv = __expf(-0.5f * t);
        float gn = dpp_wave_shl1(gv);   // G[u][lane+1] (lane63 garbage, never read)
        float dcur = gn - gv;
        if (u > 0) binc[(u - 1) * S2 + lane] = (_Float16)(0.25f * (dcur - dprev));
        dprev = dcur;
    }
    __syncthreads();

    // Goursat PDE, diagonals d = 1..252 of the 127x127 K grid. Lane l owns
    // rows iE=2l, iO=2l+1. Boundary K=1 and zero-outside emerge from the seed:
    // p1 = diag(0) = {K[0,0]=1}, p2 = diag(-1) = 0, DPP feeds 0 into lane 0.
    // Out-of-range inc reads (clamped) are always multiplied by exact zero.
    const int rE = max(lane - 1, 0);
    const int rO = min(lane, 62);
    const _Float16* pE = binc + rE * S2;
    const _Float16* pO = binc + rO * S2;

    // Body k covers d = 2k-1, 2k. Both substeps use E[k] = pE[clamp(k-1-l)];
    // O uses O[k-1] then O[k], O[k] = pO[clamp(k-1-l)]. 2 reads per body.
    int c1 = min(max(1 - 1 - lane, 0), 62);
    int c2 = min(max(2 - 1 - lane, 0), 62);
    int c3 = min(max(3 - 1 - lane, 0), 62);
    float eC  = (float)pE[c1];
    float oC  = (float)pO[c1];
    float oP  = 0.0f;               // O[0]: multiplied by p2E=0 at first use
    float eN1 = (float)pE[c2], oN1 = (float)pO[c2];
    float eN2 = (float)pE[c3], oN2 = (float)pO[c3];

    float p1E = (lane == 0) ? 1.0f : 0.0f;  // diag 0
    float p1O = 0.0f;
    float p2E = 0.0f;                        // diag -1
    float up2 = 0.0f;                        // shr1(p2O) carried from prev step

    for (int k = 1; k <= 126; ++k) {
        // d = 2k-1
        float up1 = dpp_wave_shr1(p1O);
        float cE = (up1 - up2) + p1E + up2 * eC;   // up1+p1E+up2*(inc-1)
        float cO = (p1E - p2E) + p1O + p2E * oP;
        up2 = up1; p2E = p1E; p1E = cE; p1O = cO;
        // d = 2k
        up1 = dpp_wave_shr1(p1O);
        cE = (up1 - up2) + p1E + up2 * eC;
        cO = (p1E - p2E) + p1O + p2E * oC;
        up2 = up1; p2E = p1E; p1E = cE; p1O = cO;
        // rotate software pipeline (depth 2) and prefetch body k+2
        oP = oC; eC = eN1; oC = oN1; eN1 = eN2; oN1 = oN2;
        int cn = min(max(k + 2 - lane, 0), 62);    // c(k+3) = clamp(k+3-1-lane)
        eN2 = (float)pE[cn];
        oN2 = (float)pO[cn];
    }

    // K[126,126] lives in lane 63's E slot after d=252.
    if (lane == 63) {
        float wgt = (g == 1) ? (-2.0f / 1024.0f) : (1.0f / 1024.0f);
        atomicAdd(out, wgt * p1E);
    }
}

extern "C" void kernel_launch(void* const* d_in, const int* in_sizes, int n_in,
                              void* d_out, int out_size, void* d_ws, size_t ws_size,
                              hipStream_t stream) {
    const float* x = (const float*)d_in[0];
    const float* y = (const float*)d_in[1];
    float* out = (float*)d_out;
    (void)in_sizes; (void)n_in; (void)out_size; (void)d_ws; (void)ws_size;

    hipLaunchKernelGGL(zero_kernel, dim3(1), dim3(1), 0, stream, out);
    hipLaunchKernelGGL(sigpde_kernel, dim3(3072), dim3(64), 0, stream, x, y, out);
}

// Round 3
// 91.484 us; speedup vs baseline: 1.6503x; 1.1573x over previous
//
#include <hip/hip_runtime.h>
#include <hip/hip_fp16.h>

// Signature-kernel MMD, fused. R3: 2 pairs per wave (ILP to hide LDS/DPP
// latency), grid 1536 = exactly 6 single-wave blocks/CU; k-loop unrolled x2
// bodies with software-pipelined fp16 LDS reads (depth 2 iters); clamps
// removed via zero-padded LDS (out-of-range reads are finite and provably
// multiplied by exact 0).

constexpr int S2  = 66;     // fp16 elems per binc row
constexpr int PAD = 64;     // front pad (covers negative column indices)
constexpr int BNA = 4368;   // fp16 elems per pair buffer (PAD + 63*66 + rear pad, 16B-mult)

__global__ void zero_kernel(float* out) { out[0] = 0.0f; }

__device__ __forceinline__ float dpp_shr1(float v) {
    // result[l] = src[l-1], result[0] = 0
    return __builtin_bit_cast(float,
        __builtin_amdgcn_update_dpp(0, __builtin_bit_cast(int, v), 0x138, 0xF, 0xF, true));
}
__device__ __forceinline__ float dpp_shl1(float v) {
    // result[l] = src[l+1], result[63] = 0
    return __builtin_bit_cast(float,
        __builtin_amdgcn_update_dpp(0, __builtin_bit_cast(int, v), 0x130, 0xF, 0xF, true));
}

__device__ __forceinline__ float dot4(float4 a, float4 b) {
    return a.x * b.x + a.y * b.y + a.z * b.z + a.w * b.w;
}

// Two PDE substeps (antidiagonals 2k-1, 2k) for one pair.
#define BODY(p1E, p1O, p2E, up2, oP, ef, of) {        \
    float up1 = dpp_shr1(p1O);                         \
    float cE  = (up1 - up2) + p1E + up2 * ef;          \
    float cO  = (p1E - p2E) + p1O + p2E * oP;          \
    float nu2 = up1, np2 = p1E;                        \
    p1E = cE; p1O = cO;                                \
    up1 = dpp_shr1(p1O);                               \
    cE  = (up1 - nu2) + p1E + nu2 * ef;                \
    cO  = (p1E - np2) + p1O + np2 * of;                \
    up2 = up1; p2E = p1E; p1E = cE; p1O = cO;          \
    oP  = of; }

__global__ __launch_bounds__(64) void sigpde_kernel(const float* __restrict__ x,
                                                    const float* __restrict__ y,
                                                    float* __restrict__ out) {
    __shared__ _Float16 binc0[BNA], binc1[BNA];
    __shared__ float4 xs0[64], xs1[64];
    __shared__ float  xx0[64], xx1[64];

    const int lane = threadIdx.x;
    const int q0 = blockIdx.x;          // pair 0 id
    const int q1 = blockIdx.x + 1536;   // pair 1 id

    const int g0 = q0 >> 10, a0 = (q0 & 1023) >> 5, b0 = q0 & 31;
    const int g1 = q1 >> 10, a1 = (q1 & 1023) >> 5, b1 = q1 & 31;
    const float* A0 = (g0 == 2) ? y : x;  const float* B0 = (g0 == 0) ? x : y;
    const float* A1 = (g1 == 2) ? y : x;  const float* B1 = (g1 == 0) ? x : y;

    float4 xa0 = ((const float4*)(A0 + a0 * 256))[lane];
    float4 yv0 = ((const float4*)(B0 + b0 * 256))[lane];
    float4 xa1 = ((const float4*)(A1 + a1 * 256))[lane];
    float4 yv1 = ((const float4*)(B1 + b1 * 256))[lane];
    xs0[lane] = xa0; xx0[lane] = dot4(xa0, xa0);
    xs1[lane] = xa1; xx1[lane] = dot4(xa1, xa1);
    const float yy0 = dot4(yv0, yv0);
    const float yy1 = dot4(yv1, yv1);

    // Blanket-zero both binc buffers (pads + inter-row gaps must be finite).
    {
        uint4* z0 = (uint4*)binc0; uint4* z1 = (uint4*)binc1;
        const uint4 zz = {0u, 0u, 0u, 0u};
        for (int i = lane; i < BNA / 8; i += 64) { z0[i] = zz; z1[i] = zz; }
    }
    __syncthreads();

    // Gram + double increments, both pairs interleaved.
    // binc[u-1][lane] = 0.25*((G[u][l+1]-G[u][l]) - (G[u-1][l+1]-G[u-1][l]))
    float dp0 = 0.0f, dp1 = 0.0f;
    #pragma unroll 4
    for (int u = 0; u < 64; ++u) {
        float4 xu0 = xs0[u], xu1 = xs1[u];
        float t0 = xx0[u] + yy0 - 2.0f * dot4(xu0, yv0);
        float t1 = xx1[u] + yy1 - 2.0f * dot4(xu1, yv1);
        float gv0 = __expf(-0.5f * t0);
        float gv1 = __expf(-0.5f * t1);
        float d0 = dpp_shl1(gv0) - gv0;
        float d1 = dpp_shl1(gv1) - gv1;
        if (u > 0) {
            binc0[PAD + (u - 1) * S2 + lane] = (_Float16)(0.25f * (d0 - dp0));
            binc1[PAD + (u - 1) * S2 + lane] = (_Float16)(0.25f * (d1 - dp1));
        }
        dp0 = d0; dp1 = d1;
    }
    __syncthreads();

    // Goursat PDE. Lane l owns rows iE=2l, iO=2l+1; body k = diagonals 2k-1,2k,
    // k = 1..126. Body k reads eP[k-1], oP[k-1] (column k-1-lane, folded into
    // the base pointer). Out-of-range columns hit zeroed pad / other rows'
    // finite data and are multiplied by exactly-zero state.
    const int rE = (lane >= 1) ? lane - 1 : 0;
    const int rO = (lane <= 62) ? lane : 62;
    const _Float16* eA = binc0 + PAD + rE * S2 - lane;
    const _Float16* oA = binc0 + PAD + rO * S2 - lane;
    const _Float16* eB = binc1 + PAD + rE * S2 - lane;
    const _Float16* oB = binc1 + PAD + rO * S2 - lane;

    float A_p1E = (lane == 0) ? 1.0f : 0.0f, A_p1O = 0.0f, A_p2E = 0.0f, A_up2 = 0.0f, A_oP = 0.0f;
    float B_p1E = (lane == 0) ? 1.0f : 0.0f, B_p1O = 0.0f, B_p2E = 0.0f, B_up2 = 0.0f, B_oP = 0.0f;

    // Warmup: bodies 1,2 converted; bodies 3,4 in flight.
    _Float16 hAe2 = eA[2], hAo2 = oA[2], hAe3 = eA[3], hAo3 = oA[3];
    _Float16 hBe2 = eB[2], hBo2 = oB[2], hBe3 = eB[3], hBo3 = oB[3];
    float fAe0 = (float)eA[0], fAo0 = (float)oA[0], fAe1 = (float)eA[1], fAo1 = (float)oA[1];
    float fBe0 = (float)eB[0], fBo0 = (float)oB[0], fBe1 = (float)eB[1], fBo1 = (float)oB[1];

    #pragma unroll 2
    for (int k = 1; k <= 125; k += 2) {
        // convert in-flight (bodies k+2, k+3)
        float fAe2 = (float)hAe2, fAo2 = (float)hAo2, fAe3 = (float)hAe3, fAo3 = (float)hAo3;
        float fBe2 = (float)hBe2, fBo2 = (float)hBo2, fBe3 = (float)hBe3, fBo3 = (float)hBo3;
        // prefetch bodies k+4, k+5
        hAe2 = eA[k + 3]; hAo2 = oA[k + 3]; hAe3 = eA[k + 4]; hAo3 = oA[k + 4];
        hBe2 = eB[k + 3]; hBo2 = oB[k + 3]; hBe3 = eB[k + 4]; hBo3 = oB[k + 4];
        // compute 2 bodies x 2 pairs, interleaved
        BODY(A_p1E, A_p1O, A_p2E, A_up2, A_oP, fAe0, fAo0)
        BODY(B_p1E, B_p1O, B_p2E, B_up2, B_oP, fBe0, fBo0)
        BODY(A_p1E, A_p1O, A_p2E, A_up2, A_oP, fAe1, fAo1)
        BODY(B_p1E, B_p1O, B_p2E, B_up2, B_oP, fBe1, fBo1)
        // rotate pipeline
        fAe0 = fAe2; fAo0 = fAo2; fAe1 = fAe3; fAo1 = fAo3;
        fBe0 = fBe2; fBo0 = fBo2; fBe1 = fBe3; fBo1 = fBo3;
    }

    // K[126,126] = lane 63's E slot after diagonal 252.
    if (lane == 63) {
        float w0 = (g0 == 1) ? (-2.0f / 1024.0f) : (1.0f / 1024.0f);
        float w1 = (g1 == 1) ? (-2.0f / 1024.0f) : (1.0f / 1024.0f);
        atomicAdd(out, w0 * A_p1E + w1 * B_p1E);
    }
}

extern "C" void kernel_launch(void* const* d_in, const int* in_sizes, int n_in,
                              void* d_out, int out_size, void* d_ws, size_t ws_size,
                              hipStream_t stream) {
    const float* x = (const float*)d_in[0];
    const float* y = (const float*)d_in[1];
    float* out = (float*)d_out;
    (void)in_sizes; (void)n_in; (void)out_size; (void)d_ws; (void)ws_size;

    hipLaunchKernelGGL(zero_kernel, dim3(1), dim3(1), 0, stream, out);
    hipLaunchKernelGGL(sigpde_kernel, dim3(1536), dim3(64), 0, stream, x, y, out);
}